// Round 1
// baseline (534.370 us; speedup 1.0000x reference)
//
#include <hip/hip_runtime.h>
#include <math.h>

// Problem constants
#define NB 2
#define SEQ 2048
#define HDIM 2048
#define NHD 16
#define NKVH 4
#define HEADD 128
#define MROWS (NB*SEQ)          // 4096
#define NQCOLS (NHD*HEADD)      // 2048
#define NKVCOLS (2*NKVH*HEADD)  // 1024

typedef unsigned short ushortT;
typedef __attribute__((ext_vector_type(8))) short short8;
typedef __attribute__((ext_vector_type(4))) float floatx4;
typedef __attribute__((ext_vector_type(4))) unsigned short ushort4v;

__device__ __forceinline__ ushortT f2bf(float f) {
  union { float f; unsigned int u; } v; v.f = f;
  unsigned int r = v.u + 0x7FFFu + ((v.u >> 16) & 1u);
  return (ushortT)(r >> 16);
}
__device__ __forceinline__ float bf2f(ushortT u) {
  union { unsigned int u; float f; } v; v.u = ((unsigned int)u) << 16;
  return v.f;
}

// ---------------- cast fp32 -> bf16 (vectorized) ----------------
__global__ __launch_bounds__(256) void cast_bf16_kernel(
    const float* __restrict__ in, ushortT* __restrict__ out, int n4) {
  int i = blockIdx.x * 256 + threadIdx.x;
  if (i >= n4) return;
  float4 v = ((const float4*)in)[i];
  ushort4v o;
  o.x = f2bf(v.x); o.y = f2bf(v.y); o.z = f2bf(v.z); o.w = f2bf(v.w);
  ((ushort4v*)out)[i] = o;
}

// ---------------- transpose + cast: fp32 (R,C) -> bf16 (C,R) ----------------
__global__ __launch_bounds__(256) void transpose_cast_kernel(
    const float* __restrict__ in, ushortT* __restrict__ out, int R, int C) {
  __shared__ ushortT tile[32][33];
  int c0 = blockIdx.x * 32, r0 = blockIdx.y * 32;
  int tx = threadIdx.x & 31, ty = threadIdx.x >> 5;  // ty 0..7
#pragma unroll
  for (int i = 0; i < 4; ++i)
    tile[ty + i*8][tx] = f2bf(in[(size_t)(r0 + ty + i*8) * C + c0 + tx]);
  __syncthreads();
#pragma unroll
  for (int i = 0; i < 4; ++i)
    out[(size_t)(c0 + ty + i*8) * R + r0 + tx] = tile[tx][ty + i*8];
}

// ---------------- GEMM: C(MxN) = A(MxK) * Bt(NxK)^T, bf16 in, bf16/fp32 out ----
// 128x128 tile, BK=64, 4 waves (2x2 of 64x64), mfma 16x16x32 bf16.
__global__ __launch_bounds__(256) void gemm_bt_kernel(
    const ushortT* __restrict__ A, const ushortT* __restrict__ Bt,
    void* __restrict__ C, int M, int N, int K, int c_fp32) {
  __shared__ __align__(16) ushortT lA[128 * 72];
  __shared__ __align__(16) ushortT lB[128 * 72];
  const int m0 = blockIdx.y * 128;
  const int n0 = blockIdx.x * 128;
  const int tid = threadIdx.x;
  const int wave = tid >> 6, lane = tid & 63;
  const int g = lane >> 4, l15 = lane & 15;
  const int wm = (wave >> 1) * 64, wn = (wave & 1) * 64;

  floatx4 acc[4][4] = {};

  for (int kt = 0; kt < K; kt += 64) {
    __syncthreads();
#pragma unroll
    for (int i = 0; i < 4; ++i) {
      int idx = i * 256 + tid;      // 0..1023
      int r = idx >> 3, c8 = idx & 7;
      short8 av = *(const short8*)(A + (size_t)(m0 + r) * K + kt + c8 * 8);
      *(short8*)(lA + r * 72 + c8 * 8) = av;
      short8 bv = *(const short8*)(Bt + (size_t)(n0 + r) * K + kt + c8 * 8);
      *(short8*)(lB + r * 72 + c8 * 8) = bv;
    }
    __syncthreads();
#pragma unroll
    for (int ks = 0; ks < 2; ++ks) {
      short8 af[4], bfv[4];
#pragma unroll
      for (int t = 0; t < 4; ++t) {
        af[t]  = *(const short8*)(lA + (wm + t * 16 + l15) * 72 + ks * 32 + g * 8);
        bfv[t] = *(const short8*)(lB + (wn + t * 16 + l15) * 72 + ks * 32 + g * 8);
      }
#pragma unroll
      for (int mt = 0; mt < 4; ++mt)
#pragma unroll
        for (int nt = 0; nt < 4; ++nt)
          acc[mt][nt] = __builtin_amdgcn_mfma_f32_16x16x32_bf16(
              af[mt], bfv[nt], acc[mt][nt], 0, 0, 0);
    }
  }

  // epilogue: C/D layout col=lane&15, row=(lane>>4)*4+reg
#pragma unroll
  for (int mt = 0; mt < 4; ++mt)
#pragma unroll
    for (int nt = 0; nt < 4; ++nt)
#pragma unroll
      for (int r = 0; r < 4; ++r) {
        int row = m0 + wm + mt * 16 + g * 4 + r;
        int col = n0 + wn + nt * 16 + l15;
        float v = acc[mt][nt][r];
        if (c_fp32) ((float*)C)[(size_t)row * N + col] = v;
        else ((ushortT*)C)[(size_t)row * N + col] = f2bf(v);
      }
}

// ---------------- RoPE Q: (B,S,NH*HD) bf16 -> (B,NH,S,HD) bf16 ----------------
__global__ __launch_bounds__(256) void rope_q_kernel(
    const ushortT* __restrict__ Qtmp, const float* __restrict__ cosT,
    const float* __restrict__ sinT, ushortT* __restrict__ Qr) {
  int idx = blockIdx.x * 256 + threadIdx.x;   // B*S*NH*64 total
  int d = idx & 63;
  int t = idx >> 6;          // (b*S+s)*NH + h
  int h = t & (NHD - 1);
  int bs = t >> 4;           // b*S + s
  int s = bs & (SEQ - 1);
  int b = bs >> 11;
  float c = cosT[s * HEADD + d], sn = sinT[s * HEADD + d];
  float q1 = bf2f(Qtmp[(size_t)bs * NQCOLS + h * HEADD + d]);
  float q2 = bf2f(Qtmp[(size_t)bs * NQCOLS + h * HEADD + d + 64]);
  size_t o = ((size_t)(b * NHD + h) * SEQ + s) * HEADD + d;
  Qr[o]      = f2bf(q1 * c - q2 * sn);
  Qr[o + 64] = f2bf(q2 * c + q1 * sn);
}

// ---------------- RoPE K: KVtmp cols [0,512) -> (B,NKV,S,HD) bf16 --------------
__global__ __launch_bounds__(256) void rope_k_kernel(
    const ushortT* __restrict__ KVtmp, const float* __restrict__ cosT,
    const float* __restrict__ sinT, ushortT* __restrict__ Kr) {
  int idx = blockIdx.x * 256 + threadIdx.x;   // B*S*NKV*64 total
  int d = idx & 63;
  int t = idx >> 6;          // (b*S+s)*NKV + kvh
  int kvh = t & (NKVH - 1);
  int bs = t >> 2;
  int s = bs & (SEQ - 1);
  int b = bs >> 11;
  float c = cosT[s * HEADD + d], sn = sinT[s * HEADD + d];
  float k1 = bf2f(KVtmp[(size_t)bs * NKVCOLS + kvh * HEADD + d]);
  float k2 = bf2f(KVtmp[(size_t)bs * NKVCOLS + kvh * HEADD + d + 64]);
  size_t o = ((size_t)(b * NKVH + kvh) * SEQ + s) * HEADD + d;
  Kr[o]      = f2bf(k1 * c - k2 * sn);
  Kr[o + 64] = f2bf(k2 * c + k1 * sn);
}

// ---------------- V relayout: KVtmp cols [512,1024) -> (B,NKV,HD,S) ------------
__global__ __launch_bounds__(256) void v_relayout_kernel(
    const ushortT* __restrict__ KVtmp, ushortT* __restrict__ Vt) {
  __shared__ ushortT tile[32][33];
  int bk = blockIdx.z;             // b*NKV + kvh
  int b = bk >> 2, kvh = bk & 3;
  int s0 = blockIdx.x * 32, d0 = blockIdx.y * 32;
  int tx = threadIdx.x & 31, ty = threadIdx.x >> 5;
#pragma unroll
  for (int i = 0; i < 4; ++i) {
    int s = s0 + ty + i * 8;
    tile[ty + i * 8][tx] =
        KVtmp[(size_t)(b * SEQ + s) * NKVCOLS + 512 + kvh * HEADD + d0 + tx];
  }
  __syncthreads();
#pragma unroll
  for (int i = 0; i < 4; ++i) {
    int d = d0 + ty + i * 8;
    Vt[((size_t)bk * HEADD + d) * SEQ + s0 + tx] = tile[tx][ty + i * 8];
  }
}

// ---------------- Flash attention (causal, GQA) --------------------------------
// grid (S/64, B*NH); 256 threads = 4 waves, each wave owns 16 q-rows.
__global__ __launch_bounds__(256) void attn_kernel(
    const ushortT* __restrict__ Q,   // (B,NH,S,HD)
    const ushortT* __restrict__ Kg,  // (B,NKV,S,HD)
    const ushortT* __restrict__ Vg,  // (B,NKV,HD,S)
    ushortT* __restrict__ Oa) {      // (B,S,NH*HD)
  __shared__ __align__(16) ushortT lK[64 * 136];   // key x d (pad 136)
  __shared__ __align__(16) ushortT lV[128 * 72];   // d x key (pad 72)
  __shared__ __align__(16) ushortT lP[4 * 16 * 72];

  const int tid = threadIdx.x;
  const int w = tid >> 6, lane = tid & 63;
  const int g = lane >> 4, l15 = lane & 15;
  const int bh = blockIdx.y;
  const int b = bh >> 4, h = bh & 15;
  const int kvh = h >> 2;
  const int q0 = blockIdx.x << 6;
  const int qw = q0 + w * 16;

  const float SC = 0.08838834764831845f * 1.4426950408889634f;  // 1/sqrt(128)*log2(e)

  short8 qf[4];
  {
    const ushortT* qp = Q + (((size_t)(b * NHD + h)) * SEQ + qw + l15) * HEADD + g * 8;
#pragma unroll
    for (int ks = 0; ks < 4; ++ks) qf[ks] = *(const short8*)(qp + ks * 32);
  }

  floatx4 o[8] = {};
  float m_r[4], l_r[4];
#pragma unroll
  for (int r = 0; r < 4; ++r) { m_r[r] = -INFINITY; l_r[r] = 0.f; }

  const ushortT* kbase = Kg + ((size_t)(b * NKVH + kvh)) * SEQ * HEADD;
  const ushortT* vbase = Vg + ((size_t)(b * NKVH + kvh)) * HEADD * SEQ;

  const int ktmax = blockIdx.x;
  for (int kt = 0; kt <= ktmax; ++kt) {
    __syncthreads();
    // stage K tile: 64 keys x 128 d
#pragma unroll
    for (int i = 0; i < 4; ++i) {
      int idx = i * 256 + tid;
      int r = idx >> 4, d8 = idx & 15;
      short8 v = *(const short8*)(kbase + (size_t)(kt * 64 + r) * HEADD + d8 * 8);
      *(short8*)(lK + r * 136 + d8 * 8) = v;
    }
    // stage V^T tile: 128 d x 64 keys
#pragma unroll
    for (int i = 0; i < 4; ++i) {
      int idx = i * 256 + tid;
      int d = idx >> 3, s8 = idx & 7;
      short8 v = *(const short8*)(vbase + (size_t)d * SEQ + kt * 64 + s8 * 8);
      *(short8*)(lV + d * 72 + s8 * 8) = v;
    }
    __syncthreads();

    // S = Q K^T  (16x64 per wave)
    floatx4 sc[4] = {};
#pragma unroll
    for (int ks = 0; ks < 4; ++ks)
#pragma unroll
      for (int nt = 0; nt < 4; ++nt) {
        short8 bfv = *(const short8*)(lK + (nt * 16 + l15) * 136 + ks * 32 + g * 8);
        sc[nt] = __builtin_amdgcn_mfma_f32_16x16x32_bf16(qf[ks], bfv, sc[nt], 0, 0, 0);
      }

    float p[4][4];
    float mx[4] = {-INFINITY, -INFINITY, -INFINITY, -INFINITY};
#pragma unroll
    for (int nt = 0; nt < 4; ++nt)
#pragma unroll
      for (int r = 0; r < 4; ++r) {
        float v = sc[nt][r] * SC;
        if (kt == ktmax) {
          int lrow = w * 16 + g * 4 + r;
          int lcol = nt * 16 + l15;
          if (lcol > lrow) v = -INFINITY;
        }
        p[nt][r] = v;
        mx[r] = fmaxf(mx[r], v);
      }
#pragma unroll
    for (int off = 1; off < 16; off <<= 1)
#pragma unroll
      for (int r = 0; r < 4; ++r) mx[r] = fmaxf(mx[r], __shfl_xor(mx[r], off));

    float alpha[4], rs[4];
#pragma unroll
    for (int r = 0; r < 4; ++r) {
      float mn = fmaxf(m_r[r], mx[r]);
      alpha[r] = __builtin_amdgcn_exp2f(m_r[r] - mn);
      m_r[r] = mn;
      rs[r] = 0.f;
    }
#pragma unroll
    for (int nt = 0; nt < 4; ++nt)
#pragma unroll
      for (int r = 0; r < 4; ++r) {
        float e = __builtin_amdgcn_exp2f(p[nt][r] - m_r[r]);
        p[nt][r] = e;
        rs[r] += e;
      }
#pragma unroll
    for (int off = 1; off < 16; off <<= 1)
#pragma unroll
      for (int r = 0; r < 4; ++r) rs[r] += __shfl_xor(rs[r], off);
#pragma unroll
    for (int r = 0; r < 4; ++r) l_r[r] = l_r[r] * alpha[r] + rs[r];
#pragma unroll
    for (int dt = 0; dt < 8; ++dt)
#pragma unroll
      for (int r = 0; r < 4; ++r) o[dt][r] *= alpha[r];

    // P: C-layout -> A-layout via per-wave LDS round-trip
    ushortT* pw = lP + w * 16 * 72;
#pragma unroll
    for (int nt = 0; nt < 4; ++nt)
#pragma unroll
      for (int r = 0; r < 4; ++r)
        pw[(g * 4 + r) * 72 + nt * 16 + l15] = f2bf(p[nt][r]);

    // O += P V
#pragma unroll
    for (int ks = 0; ks < 2; ++ks) {
      short8 af = *(const short8*)(pw + l15 * 72 + ks * 32 + g * 8);
#pragma unroll
      for (int dt = 0; dt < 8; ++dt) {
        short8 bfv = *(const short8*)(lV + (dt * 16 + l15) * 72 + ks * 32 + g * 8);
        o[dt] = __builtin_amdgcn_mfma_f32_16x16x32_bf16(af, bfv, o[dt], 0, 0, 0);
      }
    }
  }

  // epilogue: divide by l, write (B,S,NH*HD) bf16
#pragma unroll
  for (int dt = 0; dt < 8; ++dt)
#pragma unroll
    for (int r = 0; r < 4; ++r) {
      int row = qw + g * 4 + r;
      int col = h * HEADD + dt * 16 + l15;
      float v = o[dt][r] / l_r[r];
      Oa[(size_t)(b * SEQ + row) * NQCOLS + col] = f2bf(v);
    }
}

extern "C" void kernel_launch(void* const* d_in, const int* in_sizes, int n_in,
                              void* d_out, int out_size, void* d_ws, size_t ws_size,
                              hipStream_t stream) {
  const float* x    = (const float*)d_in[0];
  const float* cosT = (const float*)d_in[1];
  const float* sinT = (const float*)d_in[2];
  const float* Wq   = (const float*)d_in[3];
  const float* Wkv  = (const float*)d_in[4];
  const float* Wo   = (const float*)d_in[5];

  char* ws = (char*)d_ws;
  // workspace layout (bytes)
  ushortT* x_bf  = (ushortT*)(ws + 0);          // 16777216
  ushortT* Wqt   = (ushortT*)(ws + 16777216);   //  8388608
  ushortT* Wkvt  = (ushortT*)(ws + 25165824);   //  4194304
  ushortT* Wot   = (ushortT*)(ws + 29360128);   //  8388608
  ushortT* Qtmp  = (ushortT*)(ws + 37748736);   // 16777216 (aliased by Oattn)
  ushortT* KVtmp = (ushortT*)(ws + 54525952);   //  8388608
  ushortT* Qr    = (ushortT*)(ws + 62914560);   // 16777216
  ushortT* Kr    = (ushortT*)(ws + 79691776);   //  4194304
  ushortT* Vt    = (ushortT*)(ws + 83886080);   //  4194304
  ushortT* Oattn = Qtmp;                        // total 88080384

  // 1) casts / weight transposes
  cast_bf16_kernel<<<8192, 256, 0, stream>>>(x, x_bf, (MROWS * HDIM) / 4);
  transpose_cast_kernel<<<dim3(64, 64), 256, 0, stream>>>(Wq, Wqt, HDIM, NQCOLS);
  transpose_cast_kernel<<<dim3(32, 64), 256, 0, stream>>>(Wkv, Wkvt, HDIM, NKVCOLS);
  transpose_cast_kernel<<<dim3(64, 64), 256, 0, stream>>>(Wo, Wot, NQCOLS, HDIM);

  // 2) projections
  gemm_bt_kernel<<<dim3(16, 32), 256, 0, stream>>>(x_bf, Wqt, Qtmp, MROWS, NQCOLS, HDIM, 0);
  gemm_bt_kernel<<<dim3(8, 32), 256, 0, stream>>>(x_bf, Wkvt, KVtmp, MROWS, NKVCOLS, HDIM, 0);

  // 3) rope + relayout
  rope_q_kernel<<<16384, 256, 0, stream>>>(Qtmp, cosT, sinT, Qr);
  rope_k_kernel<<<4096, 256, 0, stream>>>(KVtmp, cosT, sinT, Kr);
  v_relayout_kernel<<<dim3(64, 4, 8), 256, 0, stream>>>(KVtmp, Vt);

  // 4) attention
  attn_kernel<<<dim3(32, 32), 256, 0, stream>>>(Qr, Kr, Vt, Oattn);

  // 5) output projection (fp32 out)
  gemm_bt_kernel<<<dim3(16, 32), 256, 0, stream>>>(Oattn, Wot, d_out, MROWS, HDIM, NQCOLS, 1);
}

// Round 2
// 422.982 us; speedup vs baseline: 1.2633x; 1.2633x over previous
//
#include <hip/hip_runtime.h>
#include <math.h>

// Problem constants
#define NB 2
#define SEQ 2048
#define HDIM 2048
#define NHD 16
#define NKVH 4
#define HEADD 128
#define MROWS (NB*SEQ)          // 4096
#define NQCOLS (NHD*HEADD)      // 2048
#define NKVCOLS (2*NKVH*HEADD)  // 1024

typedef unsigned short ushortT;
typedef __attribute__((ext_vector_type(8))) short short8;
typedef __attribute__((ext_vector_type(4))) float floatx4;
typedef __attribute__((ext_vector_type(4))) unsigned short ushort4v;

__device__ __forceinline__ ushortT f2bf(float f) {
  union { float f; unsigned int u; } v; v.f = f;
  unsigned int r = v.u + 0x7FFFu + ((v.u >> 16) & 1u);
  return (ushortT)(r >> 16);
}
__device__ __forceinline__ float bf2f(ushortT u) {
  union { unsigned int u; float f; } v; v.u = ((unsigned int)u) << 16;
  return v.f;
}

// ---------------- cast fp32 -> bf16 (vectorized) ----------------
__global__ __launch_bounds__(256) void cast_bf16_kernel(
    const float* __restrict__ in, ushortT* __restrict__ out, int n4) {
  int i = blockIdx.x * 256 + threadIdx.x;
  if (i >= n4) return;
  float4 v = ((const float4*)in)[i];
  ushort4v o;
  o.x = f2bf(v.x); o.y = f2bf(v.y); o.z = f2bf(v.z); o.w = f2bf(v.w);
  ((ushort4v*)out)[i] = o;
}

// ---------------- transpose + cast: fp32 (R,C) -> bf16 (C,R) ----------------
__global__ __launch_bounds__(256) void transpose_cast_kernel(
    const float* __restrict__ in, ushortT* __restrict__ out, int R, int C) {
  __shared__ ushortT tile[32][33];
  int c0 = blockIdx.x * 32, r0 = blockIdx.y * 32;
  int tx = threadIdx.x & 31, ty = threadIdx.x >> 5;  // ty 0..7
#pragma unroll
  for (int i = 0; i < 4; ++i)
    tile[ty + i*8][tx] = f2bf(in[(size_t)(r0 + ty + i*8) * C + c0 + tx]);
  __syncthreads();
#pragma unroll
  for (int i = 0; i < 4; ++i)
    out[(size_t)(c0 + ty + i*8) * R + r0 + tx] = tile[tx][ty + i*8];
}

// ---------------- GEMM: C(MxN) = A(MxK) * Bt(NxK)^T, bf16 in, bf16/fp32 out ----
// 128x128 tile, BK=64, 4 waves (2x2 of 64x64), mfma 16x16x32 bf16.
__global__ __launch_bounds__(256) void gemm_bt_kernel(
    const ushortT* __restrict__ A, const ushortT* __restrict__ Bt,
    void* __restrict__ C, int M, int N, int K, int c_fp32) {
  __shared__ __align__(16) ushortT lA[128 * 72];
  __shared__ __align__(16) ushortT lB[128 * 72];
  const int m0 = blockIdx.y * 128;
  const int n0 = blockIdx.x * 128;
  const int tid = threadIdx.x;
  const int wave = tid >> 6, lane = tid & 63;
  const int g = lane >> 4, l15 = lane & 15;
  const int wm = (wave >> 1) * 64, wn = (wave & 1) * 64;

  floatx4 acc[4][4] = {};

  for (int kt = 0; kt < K; kt += 64) {
    __syncthreads();
#pragma unroll
    for (int i = 0; i < 4; ++i) {
      int idx = i * 256 + tid;      // 0..1023
      int r = idx >> 3, c8 = idx & 7;
      short8 av = *(const short8*)(A + (size_t)(m0 + r) * K + kt + c8 * 8);
      *(short8*)(lA + r * 72 + c8 * 8) = av;
      short8 bv = *(const short8*)(Bt + (size_t)(n0 + r) * K + kt + c8 * 8);
      *(short8*)(lB + r * 72 + c8 * 8) = bv;
    }
    __syncthreads();
#pragma unroll
    for (int ks = 0; ks < 2; ++ks) {
      short8 af[4], bfv[4];
#pragma unroll
      for (int t = 0; t < 4; ++t) {
        af[t]  = *(const short8*)(lA + (wm + t * 16 + l15) * 72 + ks * 32 + g * 8);
        bfv[t] = *(const short8*)(lB + (wn + t * 16 + l15) * 72 + ks * 32 + g * 8);
      }
#pragma unroll
      for (int mt = 0; mt < 4; ++mt)
#pragma unroll
        for (int nt = 0; nt < 4; ++nt)
          acc[mt][nt] = __builtin_amdgcn_mfma_f32_16x16x32_bf16(
              af[mt], bfv[nt], acc[mt][nt], 0, 0, 0);
    }
  }

  // epilogue: C/D layout col=lane&15, row=(lane>>4)*4+reg
#pragma unroll
  for (int mt = 0; mt < 4; ++mt)
#pragma unroll
    for (int nt = 0; nt < 4; ++nt)
#pragma unroll
      for (int r = 0; r < 4; ++r) {
        int row = m0 + wm + mt * 16 + g * 4 + r;
        int col = n0 + wn + nt * 16 + l15;
        float v = acc[mt][nt][r];
        if (c_fp32) ((float*)C)[(size_t)row * N + col] = v;
        else ((ushortT*)C)[(size_t)row * N + col] = f2bf(v);
      }
}

// ---------------- RoPE Q: (B,S,NH*HD) bf16 -> (B,NH,S,HD) bf16 ----------------
__global__ __launch_bounds__(256) void rope_q_kernel(
    const ushortT* __restrict__ Qtmp, const float* __restrict__ cosT,
    const float* __restrict__ sinT, ushortT* __restrict__ Qr) {
  int idx = blockIdx.x * 256 + threadIdx.x;   // B*S*NH*64 total
  int d = idx & 63;
  int t = idx >> 6;          // (b*S+s)*NH + h
  int h = t & (NHD - 1);
  int bs = t >> 4;           // b*S + s
  int s = bs & (SEQ - 1);
  int b = bs >> 11;
  float c = cosT[s * HEADD + d], sn = sinT[s * HEADD + d];
  float q1 = bf2f(Qtmp[(size_t)bs * NQCOLS + h * HEADD + d]);
  float q2 = bf2f(Qtmp[(size_t)bs * NQCOLS + h * HEADD + d + 64]);
  size_t o = ((size_t)(b * NHD + h) * SEQ + s) * HEADD + d;
  Qr[o]      = f2bf(q1 * c - q2 * sn);
  Qr[o + 64] = f2bf(q2 * c + q1 * sn);
}

// ---------------- RoPE K: KVtmp cols [0,512) -> (B,NKV,S,HD) bf16 --------------
__global__ __launch_bounds__(256) void rope_k_kernel(
    const ushortT* __restrict__ KVtmp, const float* __restrict__ cosT,
    const float* __restrict__ sinT, ushortT* __restrict__ Kr) {
  int idx = blockIdx.x * 256 + threadIdx.x;   // B*S*NKV*64 total
  int d = idx & 63;
  int t = idx >> 6;          // (b*S+s)*NKV + kvh
  int kvh = t & (NKVH - 1);
  int bs = t >> 2;
  int s = bs & (SEQ - 1);
  int b = bs >> 11;
  float c = cosT[s * HEADD + d], sn = sinT[s * HEADD + d];
  float k1 = bf2f(KVtmp[(size_t)bs * NKVCOLS + kvh * HEADD + d]);
  float k2 = bf2f(KVtmp[(size_t)bs * NKVCOLS + kvh * HEADD + d + 64]);
  size_t o = ((size_t)(b * NKVH + kvh) * SEQ + s) * HEADD + d;
  Kr[o]      = f2bf(k1 * c - k2 * sn);
  Kr[o + 64] = f2bf(k2 * c + k1 * sn);
}

// ---------------- V relayout: KVtmp cols [512,1024) -> (B,NKV,HD,S) ------------
__global__ __launch_bounds__(256) void v_relayout_kernel(
    const ushortT* __restrict__ KVtmp, ushortT* __restrict__ Vt) {
  __shared__ ushortT tile[32][33];
  int bk = blockIdx.z;             // b*NKV + kvh
  int b = bk >> 2, kvh = bk & 3;
  int s0 = blockIdx.x * 32, d0 = blockIdx.y * 32;
  int tx = threadIdx.x & 31, ty = threadIdx.x >> 5;
#pragma unroll
  for (int i = 0; i < 4; ++i) {
    int s = s0 + ty + i * 8;
    tile[ty + i * 8][tx] =
        KVtmp[(size_t)(b * SEQ + s) * NKVCOLS + 512 + kvh * HEADD + d0 + tx];
  }
  __syncthreads();
#pragma unroll
  for (int i = 0; i < 4; ++i) {
    int d = d0 + ty + i * 8;
    Vt[((size_t)bk * HEADD + d) * SEQ + s0 + tx] = tile[tx][ty + i * 8];
  }
}

// ---------------- Flash attention (causal, GQA) --------------------------------
// grid (32=bh on FAST axis, 32=balanced qtile permutation on slow axis).
// 256 threads = 4 waves, each wave owns 16 q-rows.
//
// Block->work remap rationale: with x-fastest dispatch and 256 CUs, CU c
// receives blocks {c, c+256, c+512, c+768}, i.e. all four share blockIdx.x
// and differ by 8 in blockIdx.y. Putting bh on x and a {31-i,16+i,15-i,i}
// permutation on y gives every CU exactly 66 causal K-iterations
// (longest-first), instead of 4x(same length) which ranged 4..128.
__global__ __launch_bounds__(256) void attn_kernel(
    const ushortT* __restrict__ Q,   // (B,NH,S,HD)
    const ushortT* __restrict__ Kg,  // (B,NKV,S,HD)
    const ushortT* __restrict__ Vg,  // (B,NKV,HD,S)
    ushortT* __restrict__ Oa) {      // (B,S,NH*HD)
  __shared__ __align__(16) ushortT lK[64 * 136];   // key x d (pad 136)
  __shared__ __align__(16) ushortT lV[128 * 72];   // d x key (pad 72)
  __shared__ __align__(16) ushortT lP[4 * 16 * 72];

  const int tid = threadIdx.x;
  const int w = tid >> 6, lane = tid & 63;
  const int g = lane >> 4, l15 = lane & 15;
  const int bh = blockIdx.x;                 // bh on the fast axis
  const int yi = blockIdx.y & 7, yg = blockIdx.y >> 3;
  const int qtile = (yg == 0) ? (31 - yi)    // balanced LPT permutation
                  : (yg == 1) ? (16 + yi)
                  : (yg == 2) ? (15 - yi)
                  : yi;
  const int b = bh >> 4, h = bh & 15;
  const int kvh = h >> 2;
  const int q0 = qtile << 6;
  const int qw = q0 + w * 16;

  const float SC = 0.08838834764831845f * 1.4426950408889634f;  // 1/sqrt(128)*log2(e)

  short8 qf[4];
  {
    const ushortT* qp = Q + (((size_t)(b * NHD + h)) * SEQ + qw + l15) * HEADD + g * 8;
#pragma unroll
    for (int ks = 0; ks < 4; ++ks) qf[ks] = *(const short8*)(qp + ks * 32);
  }

  floatx4 o[8] = {};
  float m_r[4], l_r[4];
#pragma unroll
  for (int r = 0; r < 4; ++r) { m_r[r] = -INFINITY; l_r[r] = 0.f; }

  const ushortT* kbase = Kg + ((size_t)(b * NKVH + kvh)) * SEQ * HEADD;
  const ushortT* vbase = Vg + ((size_t)(b * NKVH + kvh)) * HEADD * SEQ;

  const int ktmax = qtile;
  for (int kt = 0; kt <= ktmax; ++kt) {
    __syncthreads();
    // stage K tile: 64 keys x 128 d
#pragma unroll
    for (int i = 0; i < 4; ++i) {
      int idx = i * 256 + tid;
      int r = idx >> 4, d8 = idx & 15;
      short8 v = *(const short8*)(kbase + (size_t)(kt * 64 + r) * HEADD + d8 * 8);
      *(short8*)(lK + r * 136 + d8 * 8) = v;
    }
    // stage V^T tile: 128 d x 64 keys
#pragma unroll
    for (int i = 0; i < 4; ++i) {
      int idx = i * 256 + tid;
      int d = idx >> 3, s8 = idx & 7;
      short8 v = *(const short8*)(vbase + (size_t)d * SEQ + kt * 64 + s8 * 8);
      *(short8*)(lV + d * 72 + s8 * 8) = v;
    }
    __syncthreads();

    // S = Q K^T  (16x64 per wave)
    floatx4 sc[4] = {};
#pragma unroll
    for (int ks = 0; ks < 4; ++ks)
#pragma unroll
      for (int nt = 0; nt < 4; ++nt) {
        short8 bfv = *(const short8*)(lK + (nt * 16 + l15) * 136 + ks * 32 + g * 8);
        sc[nt] = __builtin_amdgcn_mfma_f32_16x16x32_bf16(qf[ks], bfv, sc[nt], 0, 0, 0);
      }

    float p[4][4];
    float mx[4] = {-INFINITY, -INFINITY, -INFINITY, -INFINITY};
#pragma unroll
    for (int nt = 0; nt < 4; ++nt)
#pragma unroll
      for (int r = 0; r < 4; ++r) {
        float v = sc[nt][r] * SC;
        if (kt == ktmax) {
          int lrow = w * 16 + g * 4 + r;
          int lcol = nt * 16 + l15;
          if (lcol > lrow) v = -INFINITY;
        }
        p[nt][r] = v;
        mx[r] = fmaxf(mx[r], v);
      }
#pragma unroll
    for (int off = 1; off < 16; off <<= 1)
#pragma unroll
      for (int r = 0; r < 4; ++r) mx[r] = fmaxf(mx[r], __shfl_xor(mx[r], off));

    float alpha[4], rs[4];
#pragma unroll
    for (int r = 0; r < 4; ++r) {
      float mn = fmaxf(m_r[r], mx[r]);
      alpha[r] = __builtin_amdgcn_exp2f(m_r[r] - mn);
      m_r[r] = mn;
      rs[r] = 0.f;
    }
#pragma unroll
    for (int nt = 0; nt < 4; ++nt)
#pragma unroll
      for (int r = 0; r < 4; ++r) {
        float e = __builtin_amdgcn_exp2f(p[nt][r] - m_r[r]);
        p[nt][r] = e;
        rs[r] += e;
      }
#pragma unroll
    for (int off = 1; off < 16; off <<= 1)
#pragma unroll
      for (int r = 0; r < 4; ++r) rs[r] += __shfl_xor(rs[r], off);
#pragma unroll
    for (int r = 0; r < 4; ++r) l_r[r] = l_r[r] * alpha[r] + rs[r];
#pragma unroll
    for (int dt = 0; dt < 8; ++dt)
#pragma unroll
      for (int r = 0; r < 4; ++r) o[dt][r] *= alpha[r];

    // P: C-layout -> A-layout via per-wave LDS round-trip
    ushortT* pw = lP + w * 16 * 72;
#pragma unroll
    for (int nt = 0; nt < 4; ++nt)
#pragma unroll
      for (int r = 0; r < 4; ++r)
        pw[(g * 4 + r) * 72 + nt * 16 + l15] = f2bf(p[nt][r]);

    // O += P V
#pragma unroll
    for (int ks = 0; ks < 2; ++ks) {
      short8 af = *(const short8*)(pw + l15 * 72 + ks * 32 + g * 8);
#pragma unroll
      for (int dt = 0; dt < 8; ++dt) {
        short8 bfv = *(const short8*)(lV + (dt * 16 + l15) * 72 + ks * 32 + g * 8);
        o[dt] = __builtin_amdgcn_mfma_f32_16x16x32_bf16(af, bfv, o[dt], 0, 0, 0);
      }
    }
  }

  // epilogue: divide by l, write (B,S,NH*HD) bf16
#pragma unroll
  for (int dt = 0; dt < 8; ++dt)
#pragma unroll
    for (int r = 0; r < 4; ++r) {
      int row = qw + g * 4 + r;
      int col = h * HEADD + dt * 16 + l15;
      float v = o[dt][r] / l_r[r];
      Oa[(size_t)(b * SEQ + row) * NQCOLS + col] = f2bf(v);
    }
}

extern "C" void kernel_launch(void* const* d_in, const int* in_sizes, int n_in,
                              void* d_out, int out_size, void* d_ws, size_t ws_size,
                              hipStream_t stream) {
  const float* x    = (const float*)d_in[0];
  const float* cosT = (const float*)d_in[1];
  const float* sinT = (const float*)d_in[2];
  const float* Wq   = (const float*)d_in[3];
  const float* Wkv  = (const float*)d_in[4];
  const float* Wo   = (const float*)d_in[5];

  char* ws = (char*)d_ws;
  // workspace layout (bytes)
  ushortT* x_bf  = (ushortT*)(ws + 0);          // 16777216
  ushortT* Wqt   = (ushortT*)(ws + 16777216);   //  8388608
  ushortT* Wkvt  = (ushortT*)(ws + 25165824);   //  4194304
  ushortT* Wot   = (ushortT*)(ws + 29360128);   //  8388608
  ushortT* Qtmp  = (ushortT*)(ws + 37748736);   // 16777216 (aliased by Oattn)
  ushortT* KVtmp = (ushortT*)(ws + 54525952);   //  8388608
  ushortT* Qr    = (ushortT*)(ws + 62914560);   // 16777216
  ushortT* Kr    = (ushortT*)(ws + 79691776);   //  4194304
  ushortT* Vt    = (ushortT*)(ws + 83886080);   //  4194304
  ushortT* Oattn = Qtmp;                        // total 88080384

  // 1) casts / weight transposes
  cast_bf16_kernel<<<8192, 256, 0, stream>>>(x, x_bf, (MROWS * HDIM) / 4);
  transpose_cast_kernel<<<dim3(64, 64), 256, 0, stream>>>(Wq, Wqt, HDIM, NQCOLS);
  transpose_cast_kernel<<<dim3(32, 64), 256, 0, stream>>>(Wkv, Wkvt, HDIM, NKVCOLS);
  transpose_cast_kernel<<<dim3(64, 64), 256, 0, stream>>>(Wo, Wot, NQCOLS, HDIM);

  // 2) projections
  gemm_bt_kernel<<<dim3(16, 32), 256, 0, stream>>>(x_bf, Wqt, Qtmp, MROWS, NQCOLS, HDIM, 0);
  gemm_bt_kernel<<<dim3(8, 32), 256, 0, stream>>>(x_bf, Wkvt, KVtmp, MROWS, NKVCOLS, HDIM, 0);

  // 3) rope + relayout
  rope_q_kernel<<<16384, 256, 0, stream>>>(Qtmp, cosT, sinT, Qr);
  rope_k_kernel<<<4096, 256, 0, stream>>>(KVtmp, cosT, sinT, Kr);
  v_relayout_kernel<<<dim3(64, 4, 8), 256, 0, stream>>>(KVtmp, Vt);

  // 4) attention
  attn_kernel<<<dim3(32, 32), 256, 0, stream>>>(Qr, Kr, Vt, Oattn);

  // 5) output projection (fp32 out)
  gemm_bt_kernel<<<dim3(16, 32), 256, 0, stream>>>(Oattn, Wot, d_out, MROWS, HDIM, NQCOLS, 1);
}

// Round 3
// 409.133 us; speedup vs baseline: 1.3061x; 1.0338x over previous
//
#include <hip/hip_runtime.h>
#include <math.h>

// Problem constants
#define NB 2
#define SEQ 2048
#define HDIM 2048
#define NHD 16
#define NKVH 4
#define HEADD 128
#define MROWS (NB*SEQ)          // 4096
#define NQCOLS (NHD*HEADD)      // 2048
#define NKVCOLS (2*NKVH*HEADD)  // 1024

typedef unsigned short ushortT;
typedef __attribute__((ext_vector_type(8))) short short8;
typedef __attribute__((ext_vector_type(4))) float floatx4;
typedef __attribute__((ext_vector_type(4))) unsigned short ushort4v;

__device__ __forceinline__ ushortT f2bf(float f) {
  union { float f; unsigned int u; } v; v.f = f;
  unsigned int r = v.u + 0x7FFFu + ((v.u >> 16) & 1u);
  return (ushortT)(r >> 16);
}
__device__ __forceinline__ float bf2f(ushortT u) {
  union { unsigned int u; float f; } v; v.u = ((unsigned int)u) << 16;
  return v.f;
}

// async global->LDS, 16B per lane. LDS dest must be wave-uniform base +
// lane*16 (m104/m108) -> LDS layout is lane-contiguous; bank-conflict
// avoidance is done by XOR-swizzling the GLOBAL chunk index instead.
__device__ __forceinline__ void gload16(const ushortT* g, ushortT* l) {
  __builtin_amdgcn_global_load_lds(
      (const __attribute__((address_space(1))) void*)g,
      (__attribute__((address_space(3))) void*)l, 16, 0, 0);
}

// ---------------- cast fp32 -> bf16 (vectorized) ----------------
__global__ __launch_bounds__(256) void cast_bf16_kernel(
    const float* __restrict__ in, ushortT* __restrict__ out, int n4) {
  int i = blockIdx.x * 256 + threadIdx.x;
  if (i >= n4) return;
  float4 v = ((const float4*)in)[i];
  ushort4v o;
  o.x = f2bf(v.x); o.y = f2bf(v.y); o.z = f2bf(v.z); o.w = f2bf(v.w);
  ((ushort4v*)out)[i] = o;
}

// ---------------- transpose + cast: fp32 (R,C) -> bf16 (C,R) ----------------
__global__ __launch_bounds__(256) void transpose_cast_kernel(
    const float* __restrict__ in, ushortT* __restrict__ out, int R, int C) {
  __shared__ ushortT tile[32][33];
  int c0 = blockIdx.x * 32, r0 = blockIdx.y * 32;
  int tx = threadIdx.x & 31, ty = threadIdx.x >> 5;  // ty 0..7
#pragma unroll
  for (int i = 0; i < 4; ++i)
    tile[ty + i*8][tx] = f2bf(in[(size_t)(r0 + ty + i*8) * C + c0 + tx]);
  __syncthreads();
#pragma unroll
  for (int i = 0; i < 4; ++i)
    out[(size_t)(c0 + ty + i*8) * R + r0 + tx] = tile[tx][ty + i*8];
}

// ---------------- GEMM: C(MxN) = A(MxK) * Bt(NxK)^T, bf16 in, bf16/fp32 out ----
// 128x128 tile, BK=64, 4 waves (2x2 of 64x64), mfma 16x16x32 bf16.
// m97-style: global_load_lds width-16 staging, unpadded LDS, global-side
// XOR swizzle (chunk ^= row&7) so fragment ds_read_b128 spans all banks.
__global__ __launch_bounds__(256) void gemm_bt_kernel(
    const ushortT* __restrict__ A, const ushortT* __restrict__ Bt,
    void* __restrict__ C, int M, int N, int K, int c_fp32) {
  __shared__ __align__(16) ushortT lA[128 * 64];
  __shared__ __align__(16) ushortT lB[128 * 64];
  const int m0 = blockIdx.y * 128;
  const int n0 = blockIdx.x * 128;
  const int tid = threadIdx.x;
  const int wave = tid >> 6, lane = tid & 63;
  const int g = lane >> 4, l15 = lane & 15;
  const int wm = (wave >> 1) * 64, wn = (wave & 1) * 64;
  const int sw = l15 & 7;                  // fragment-read swizzle key

  floatx4 acc[4][4] = {};

  for (int kt = 0; kt < K; kt += 64) {
    __syncthreads();
#pragma unroll
    for (int i = 0; i < 4; ++i) {
      int s = i * 256 + tid;               // LDS chunk slot 0..1023
      int r = s >> 3, j = s & 7;           // row, within-row chunk slot
      int col8 = j ^ (r & 7);              // swizzled global chunk
      gload16(A  + (size_t)(m0 + r) * K + kt + col8 * 8, lA + s * 8);
      gload16(Bt + (size_t)(n0 + r) * K + kt + col8 * 8, lB + s * 8);
    }
    __syncthreads();                       // compiler emits vmcnt(0) drain here
#pragma unroll
    for (int ks = 0; ks < 2; ++ks) {
      short8 af[4], bfv[4];
#pragma unroll
      for (int t = 0; t < 4; ++t) {
        af[t]  = *(const short8*)(lA + (wm + t * 16 + l15) * 64 + ((ks * 4 + g) ^ sw) * 8);
        bfv[t] = *(const short8*)(lB + (wn + t * 16 + l15) * 64 + ((ks * 4 + g) ^ sw) * 8);
      }
#pragma unroll
      for (int mt = 0; mt < 4; ++mt)
#pragma unroll
        for (int nt = 0; nt < 4; ++nt)
          acc[mt][nt] = __builtin_amdgcn_mfma_f32_16x16x32_bf16(
              af[mt], bfv[nt], acc[mt][nt], 0, 0, 0);
    }
  }

  // epilogue: C/D layout col=lane&15, row=(lane>>4)*4+reg
#pragma unroll
  for (int mt = 0; mt < 4; ++mt)
#pragma unroll
    for (int nt = 0; nt < 4; ++nt)
#pragma unroll
      for (int r = 0; r < 4; ++r) {
        int row = m0 + wm + mt * 16 + g * 4 + r;
        int col = n0 + wn + nt * 16 + l15;
        float v = acc[mt][nt][r];
        if (c_fp32) ((float*)C)[(size_t)row * N + col] = v;
        else ((ushortT*)C)[(size_t)row * N + col] = f2bf(v);
      }
}

// ---------------- RoPE Q: (B,S,NH*HD) bf16 -> (B,NH,S,HD) bf16 ----------------
__global__ __launch_bounds__(256) void rope_q_kernel(
    const ushortT* __restrict__ Qtmp, const float* __restrict__ cosT,
    const float* __restrict__ sinT, ushortT* __restrict__ Qr) {
  int idx = blockIdx.x * 256 + threadIdx.x;   // B*S*NH*64 total
  int d = idx & 63;
  int t = idx >> 6;          // (b*S+s)*NH + h
  int h = t & (NHD - 1);
  int bs = t >> 4;           // b*S + s
  int s = bs & (SEQ - 1);
  int b = bs >> 11;
  float c = cosT[s * HEADD + d], sn = sinT[s * HEADD + d];
  float q1 = bf2f(Qtmp[(size_t)bs * NQCOLS + h * HEADD + d]);
  float q2 = bf2f(Qtmp[(size_t)bs * NQCOLS + h * HEADD + d + 64]);
  size_t o = ((size_t)(b * NHD + h) * SEQ + s) * HEADD + d;
  Qr[o]      = f2bf(q1 * c - q2 * sn);
  Qr[o + 64] = f2bf(q2 * c + q1 * sn);
}

// ---------------- RoPE K: KVtmp cols [0,512) -> (B,NKV,S,HD) bf16 --------------
__global__ __launch_bounds__(256) void rope_k_kernel(
    const ushortT* __restrict__ KVtmp, const float* __restrict__ cosT,
    const float* __restrict__ sinT, ushortT* __restrict__ Kr) {
  int idx = blockIdx.x * 256 + threadIdx.x;   // B*S*NKV*64 total
  int d = idx & 63;
  int t = idx >> 6;          // (b*S+s)*NKV + kvh
  int kvh = t & (NKVH - 1);
  int bs = t >> 2;
  int s = bs & (SEQ - 1);
  int b = bs >> 11;
  float c = cosT[s * HEADD + d], sn = sinT[s * HEADD + d];
  float k1 = bf2f(KVtmp[(size_t)bs * NKVCOLS + kvh * HEADD + d]);
  float k2 = bf2f(KVtmp[(size_t)bs * NKVCOLS + kvh * HEADD + d + 64]);
  size_t o = ((size_t)(b * NKVH + kvh) * SEQ + s) * HEADD + d;
  Kr[o]      = f2bf(k1 * c - k2 * sn);
  Kr[o + 64] = f2bf(k2 * c + k1 * sn);
}

// ---------------- V relayout: KVtmp cols [512,1024) -> (B,NKV,HD,S) ------------
__global__ __launch_bounds__(256) void v_relayout_kernel(
    const ushortT* __restrict__ KVtmp, ushortT* __restrict__ Vt) {
  __shared__ ushortT tile[32][33];
  int bk = blockIdx.z;             // b*NKV + kvh
  int b = bk >> 2, kvh = bk & 3;
  int s0 = blockIdx.x * 32, d0 = blockIdx.y * 32;
  int tx = threadIdx.x & 31, ty = threadIdx.x >> 5;
#pragma unroll
  for (int i = 0; i < 4; ++i) {
    int s = s0 + ty + i * 8;
    tile[ty + i * 8][tx] =
        KVtmp[(size_t)(b * SEQ + s) * NKVCOLS + 512 + kvh * HEADD + d0 + tx];
  }
  __syncthreads();
#pragma unroll
  for (int i = 0; i < 4; ++i) {
    int d = d0 + ty + i * 8;
    Vt[((size_t)bk * HEADD + d) * SEQ + s0 + tx] = tile[tx][ty + i * 8];
  }
}

// ---------------- Flash attention (causal, GQA) --------------------------------
// grid (32=bh on FAST axis, 32=balanced qtile permutation on slow axis).
// 256 threads = 4 waves, each wave owns 16 q-rows.
// LDS = 16K (lK) + 16K (lV) + 8K (lP) = 40KB -> 4 blocks/CU.
__global__ __launch_bounds__(256) void attn_kernel(
    const ushortT* __restrict__ Q,   // (B,NH,S,HD)
    const ushortT* __restrict__ Kg,  // (B,NKV,S,HD)
    const ushortT* __restrict__ Vg,  // (B,NKV,HD,S)
    ushortT* __restrict__ Oa) {      // (B,S,NH*HD)
  __shared__ __align__(16) ushortT lK[64 * 128];   // key x d, swizzled chunks
  __shared__ __align__(16) ushortT lV[128 * 64];   // d x key, swizzled chunks
  __shared__ __align__(16) ushortT lP[4 * 16 * 64];// per-wave P, swizzled

  const int tid = threadIdx.x;
  const int w = tid >> 6, lane = tid & 63;
  const int g = lane >> 4, l15 = lane & 15;
  const int sw = l15 & 7;
  const int bh = blockIdx.x;                 // bh on the fast axis
  const int yi = blockIdx.y & 7, yg = blockIdx.y >> 3;
  const int qtile = (yg == 0) ? (31 - yi)    // balanced LPT permutation
                  : (yg == 1) ? (16 + yi)
                  : (yg == 2) ? (15 - yi)
                  : yi;
  const int b = bh >> 4, h = bh & 15;
  const int kvh = h >> 2;
  const int q0 = qtile << 6;
  const int qw = q0 + w * 16;

  const float SC = 0.08838834764831845f * 1.4426950408889634f;  // 1/sqrt(128)*log2(e)

  short8 qf[4];
  {
    const ushortT* qp = Q + (((size_t)(b * NHD + h)) * SEQ + qw + l15) * HEADD + g * 8;
#pragma unroll
    for (int ks = 0; ks < 4; ++ks) qf[ks] = *(const short8*)(qp + ks * 32);
  }

  floatx4 o[8] = {};
  float m_r[4], l_r[4];
#pragma unroll
  for (int r = 0; r < 4; ++r) { m_r[r] = -INFINITY; l_r[r] = 0.f; }

  const ushortT* kbase = Kg + ((size_t)(b * NKVH + kvh)) * SEQ * HEADD;
  const ushortT* vbase = Vg + ((size_t)(b * NKVH + kvh)) * HEADD * SEQ;

  const int ktmax = qtile;
  for (int kt = 0; kt <= ktmax; ++kt) {
    __syncthreads();
    // stage K tile (64 keys x 128 d): 1024 chunks, 16/row, swizzle ^(r&7)
#pragma unroll
    for (int i = 0; i < 4; ++i) {
      int s = i * 256 + tid;
      int r = s >> 4, j = (s & 15) ^ (s >> 4 & 7);
      gload16(kbase + (size_t)(kt * 64 + r) * HEADD + j * 8, lK + s * 8);
    }
    // stage V^T tile (128 d x 64 keys): 1024 chunks, 8/row, swizzle ^(r&7)
#pragma unroll
    for (int i = 0; i < 4; ++i) {
      int s = i * 256 + tid;
      int r = s >> 3, j = (s & 7) ^ (r & 7);
      gload16(vbase + (size_t)r * SEQ + kt * 64 + j * 8, lV + s * 8);
    }
    __syncthreads();                       // vmcnt(0) drain + barrier

    // S = Q K^T  (16x64 per wave)
    floatx4 sc[4] = {};
#pragma unroll
    for (int ks = 0; ks < 4; ++ks)
#pragma unroll
      for (int nt = 0; nt < 4; ++nt) {
        short8 bfv = *(const short8*)(lK + (nt * 16 + l15) * 128 + ((ks * 4 + g) ^ sw) * 8);
        sc[nt] = __builtin_amdgcn_mfma_f32_16x16x32_bf16(qf[ks], bfv, sc[nt], 0, 0, 0);
      }

    float p[4][4];
    float mx[4] = {-INFINITY, -INFINITY, -INFINITY, -INFINITY};
#pragma unroll
    for (int nt = 0; nt < 4; ++nt)
#pragma unroll
      for (int r = 0; r < 4; ++r) {
        float v = sc[nt][r] * SC;
        if (kt == ktmax) {
          int lrow = w * 16 + g * 4 + r;
          int lcol = nt * 16 + l15;
          if (lcol > lrow) v = -INFINITY;
        }
        p[nt][r] = v;
        mx[r] = fmaxf(mx[r], v);
      }
#pragma unroll
    for (int off = 1; off < 16; off <<= 1)
#pragma unroll
      for (int r = 0; r < 4; ++r) mx[r] = fmaxf(mx[r], __shfl_xor(mx[r], off));

    float alpha[4], rs[4];
#pragma unroll
    for (int r = 0; r < 4; ++r) {
      float mn = fmaxf(m_r[r], mx[r]);
      alpha[r] = __builtin_amdgcn_exp2f(m_r[r] - mn);
      m_r[r] = mn;
      rs[r] = 0.f;
    }
#pragma unroll
    for (int nt = 0; nt < 4; ++nt)
#pragma unroll
      for (int r = 0; r < 4; ++r) {
        float e = __builtin_amdgcn_exp2f(p[nt][r] - m_r[r]);
        p[nt][r] = e;
        rs[r] += e;
      }
#pragma unroll
    for (int off = 1; off < 16; off <<= 1)
#pragma unroll
      for (int r = 0; r < 4; ++r) rs[r] += __shfl_xor(rs[r], off);
#pragma unroll
    for (int r = 0; r < 4; ++r) l_r[r] = l_r[r] * alpha[r] + rs[r];
#pragma unroll
    for (int dt = 0; dt < 8; ++dt)
#pragma unroll
      for (int r = 0; r < 4; ++r) o[dt][r] *= alpha[r];

    // P: C-layout -> A-layout via per-wave LDS round-trip (swizzled rows)
    ushortT* pw = lP + w * 16 * 64;
#pragma unroll
    for (int nt = 0; nt < 4; ++nt)
#pragma unroll
      for (int r = 0; r < 4; ++r) {
        int prow = g * 4 + r, pc = nt * 16 + l15;
        pw[prow * 64 + (((pc >> 3) ^ (prow & 7)) * 8) + (pc & 7)] = f2bf(p[nt][r]);
      }

    // O += P V
#pragma unroll
    for (int ks = 0; ks < 2; ++ks) {
      short8 af = *(const short8*)(pw + l15 * 64 + ((ks * 4 + g) ^ sw) * 8);
#pragma unroll
      for (int dt = 0; dt < 8; ++dt) {
        short8 bfv = *(const short8*)(lV + (dt * 16 + l15) * 64 + ((ks * 4 + g) ^ sw) * 8);
        o[dt] = __builtin_amdgcn_mfma_f32_16x16x32_bf16(af, bfv, o[dt], 0, 0, 0);
      }
    }
  }

  // epilogue: divide by l, write (B,S,NH*HD) bf16
#pragma unroll
  for (int dt = 0; dt < 8; ++dt)
#pragma unroll
    for (int r = 0; r < 4; ++r) {
      int row = qw + g * 4 + r;
      int col = h * HEADD + dt * 16 + l15;
      float v = o[dt][r] / l_r[r];
      Oa[(size_t)(b * SEQ + row) * NQCOLS + col] = f2bf(v);
    }
}

extern "C" void kernel_launch(void* const* d_in, const int* in_sizes, int n_in,
                              void* d_out, int out_size, void* d_ws, size_t ws_size,
                              hipStream_t stream) {
  const float* x    = (const float*)d_in[0];
  const float* cosT = (const float*)d_in[1];
  const float* sinT = (const float*)d_in[2];
  const float* Wq   = (const float*)d_in[3];
  const float* Wkv  = (const float*)d_in[4];
  const float* Wo   = (const float*)d_in[5];

  char* ws = (char*)d_ws;
  // workspace layout (bytes)
  ushortT* x_bf  = (ushortT*)(ws + 0);          // 16777216
  ushortT* Wqt   = (ushortT*)(ws + 16777216);   //  8388608
  ushortT* Wkvt  = (ushortT*)(ws + 25165824);   //  4194304
  ushortT* Wot   = (ushortT*)(ws + 29360128);   //  8388608
  ushortT* Qtmp  = (ushortT*)(ws + 37748736);   // 16777216 (aliased by Oattn)
  ushortT* KVtmp = (ushortT*)(ws + 54525952);   //  8388608
  ushortT* Qr    = (ushortT*)(ws + 62914560);   // 16777216
  ushortT* Kr    = (ushortT*)(ws + 79691776);   //  4194304
  ushortT* Vt    = (ushortT*)(ws + 83886080);   //  4194304
  ushortT* Oattn = Qtmp;                        // total 88080384

  // 1) casts / weight transposes
  cast_bf16_kernel<<<8192, 256, 0, stream>>>(x, x_bf, (MROWS * HDIM) / 4);
  transpose_cast_kernel<<<dim3(64, 64), 256, 0, stream>>>(Wq, Wqt, HDIM, NQCOLS);
  transpose_cast_kernel<<<dim3(32, 64), 256, 0, stream>>>(Wkv, Wkvt, HDIM, NKVCOLS);
  transpose_cast_kernel<<<dim3(64, 64), 256, 0, stream>>>(Wo, Wot, NQCOLS, HDIM);

  // 2) projections
  gemm_bt_kernel<<<dim3(16, 32), 256, 0, stream>>>(x_bf, Wqt, Qtmp, MROWS, NQCOLS, HDIM, 0);
  gemm_bt_kernel<<<dim3(8, 32), 256, 0, stream>>>(x_bf, Wkvt, KVtmp, MROWS, NKVCOLS, HDIM, 0);

  // 3) rope + relayout
  rope_q_kernel<<<16384, 256, 0, stream>>>(Qtmp, cosT, sinT, Qr);
  rope_k_kernel<<<4096, 256, 0, stream>>>(KVtmp, cosT, sinT, Kr);
  v_relayout_kernel<<<dim3(64, 4, 8), 256, 0, stream>>>(KVtmp, Vt);

  // 4) attention
  attn_kernel<<<dim3(32, 32), 256, 0, stream>>>(Qr, Kr, Vt, Oattn);

  // 5) output projection (fp32 out)
  gemm_bt_kernel<<<dim3(16, 32), 256, 0, stream>>>(Oattn, Wot, d_out, MROWS, HDIM, NQCOLS, 1);
}

// Round 4
// 376.035 us; speedup vs baseline: 1.4211x; 1.0880x over previous
//
#include <hip/hip_runtime.h>
#include <math.h>

// Problem constants
#define NB 2
#define SEQ 2048
#define HDIM 2048
#define NHD 16
#define NKVH 4
#define HEADD 128
#define MROWS (NB*SEQ)          // 4096
#define NQCOLS (NHD*HEADD)      // 2048
#define QKVCOLS 3072            // fused Q (2048) + K (512) + V (512)

typedef unsigned short ushortT;
typedef __attribute__((ext_vector_type(8))) short short8;
typedef __attribute__((ext_vector_type(4))) float floatx4;
typedef __attribute__((ext_vector_type(4))) unsigned short ushort4v;

__device__ __forceinline__ ushortT f2bf(float f) {
  union { float f; unsigned int u; } v; v.f = f;
  unsigned int r = v.u + 0x7FFFu + ((v.u >> 16) & 1u);
  return (ushortT)(r >> 16);
}
__device__ __forceinline__ float bf2f(ushortT u) {
  union { unsigned int u; float f; } v; v.u = ((unsigned int)u) << 16;
  return v.f;
}

// async global->LDS, 16B per lane (LDS dest = wave-uniform base + lane*16).
__device__ __forceinline__ void gload16(const ushortT* g, ushortT* l) {
  __builtin_amdgcn_global_load_lds(
      (const __attribute__((address_space(1))) void*)g,
      (__attribute__((address_space(3))) void*)l, 16, 0, 0);
}

// ---------------- cast fp32 -> bf16 (vectorized) ----------------
__global__ __launch_bounds__(256) void cast_bf16_kernel(
    const float* __restrict__ in, ushortT* __restrict__ out, int n4) {
  int i = blockIdx.x * 256 + threadIdx.x;
  if (i >= n4) return;
  float4 v = ((const float4*)in)[i];
  ushort4v o;
  o.x = f2bf(v.x); o.y = f2bf(v.y); o.z = f2bf(v.z); o.w = f2bf(v.w);
  ((ushort4v*)out)[i] = o;
}

// ---------------- transpose + cast: fp32 (R,C) -> bf16 (C,R) ----------------
__global__ __launch_bounds__(256) void transpose_cast_kernel(
    const float* __restrict__ in, ushortT* __restrict__ out, int R, int C) {
  __shared__ ushortT tile[32][33];
  int c0 = blockIdx.x * 32, r0 = blockIdx.y * 32;
  int tx = threadIdx.x & 31, ty = threadIdx.x >> 5;  // ty 0..7
#pragma unroll
  for (int i = 0; i < 4; ++i)
    tile[ty + i*8][tx] = f2bf(in[(size_t)(r0 + ty + i*8) * C + c0 + tx]);
  __syncthreads();
#pragma unroll
  for (int i = 0; i < 4; ++i)
    out[(size_t)(c0 + ty + i*8) * R + r0 + tx] = tile[tx][ty + i*8];
}

// ---------------- GEMM: C(MxN) = A(MxK) * Bt(NxK)^T, bf16 in, bf16/fp32 out ----
// 128x128 tile, BK=64, 4 waves (2x2 of 64x64), mfma 16x16x32 bf16.
// global_load_lds width-16 staging, unpadded LDS, global-side XOR swizzle.
__global__ __launch_bounds__(256) void gemm_bt_kernel(
    const ushortT* __restrict__ A, const ushortT* __restrict__ Bt,
    void* __restrict__ C, int M, int N, int K, int c_fp32) {
  __shared__ __align__(16) ushortT lA[128 * 64];
  __shared__ __align__(16) ushortT lB[128 * 64];
  const int m0 = blockIdx.y * 128;
  const int n0 = blockIdx.x * 128;
  const int tid = threadIdx.x;
  const int wave = tid >> 6, lane = tid & 63;
  const int g = lane >> 4, l15 = lane & 15;
  const int wm = (wave >> 1) * 64, wn = (wave & 1) * 64;
  const int sw = l15 & 7;

  floatx4 acc[4][4] = {};

  for (int kt = 0; kt < K; kt += 64) {
    __syncthreads();
#pragma unroll
    for (int i = 0; i < 4; ++i) {
      int s = i * 256 + tid;
      int r = s >> 3, j = s & 7;
      int col8 = j ^ (r & 7);
      gload16(A  + (size_t)(m0 + r) * K + kt + col8 * 8, lA + s * 8);
      gload16(Bt + (size_t)(n0 + r) * K + kt + col8 * 8, lB + s * 8);
    }
    __syncthreads();
#pragma unroll
    for (int ks = 0; ks < 2; ++ks) {
      short8 af[4], bfv[4];
#pragma unroll
      for (int t = 0; t < 4; ++t) {
        af[t]  = *(const short8*)(lA + (wm + t * 16 + l15) * 64 + ((ks * 4 + g) ^ sw) * 8);
        bfv[t] = *(const short8*)(lB + (wn + t * 16 + l15) * 64 + ((ks * 4 + g) ^ sw) * 8);
      }
#pragma unroll
      for (int mt = 0; mt < 4; ++mt)
#pragma unroll
        for (int nt = 0; nt < 4; ++nt)
          acc[mt][nt] = __builtin_amdgcn_mfma_f32_16x16x32_bf16(
              af[mt], bfv[nt], acc[mt][nt], 0, 0, 0);
    }
  }

#pragma unroll
  for (int mt = 0; mt < 4; ++mt)
#pragma unroll
    for (int nt = 0; nt < 4; ++nt)
#pragma unroll
      for (int r = 0; r < 4; ++r) {
        int row = m0 + wm + mt * 16 + g * 4 + r;
        int col = n0 + wn + nt * 16 + l15;
        float v = acc[mt][nt][r];
        if (c_fp32) ((float*)C)[(size_t)row * N + col] = v;
        else ((ushortT*)C)[(size_t)row * N + col] = f2bf(v);
      }
}

// ---------------- RoPE Q: QKVtmp cols [0,2048) -> (B,NH,S,HD) bf16 -------------
__global__ __launch_bounds__(256) void rope_q_kernel(
    const ushortT* __restrict__ QKVtmp, const float* __restrict__ cosT,
    const float* __restrict__ sinT, ushortT* __restrict__ Qr) {
  int idx = blockIdx.x * 256 + threadIdx.x;   // B*S*NH*64 total
  int d = idx & 63;
  int t = idx >> 6;          // (b*S+s)*NH + h
  int h = t & (NHD - 1);
  int bs = t >> 4;           // b*S + s
  int s = bs & (SEQ - 1);
  int b = bs >> 11;
  float c = cosT[s * HEADD + d], sn = sinT[s * HEADD + d];
  float q1 = bf2f(QKVtmp[(size_t)bs * QKVCOLS + h * HEADD + d]);
  float q2 = bf2f(QKVtmp[(size_t)bs * QKVCOLS + h * HEADD + d + 64]);
  size_t o = ((size_t)(b * NHD + h) * SEQ + s) * HEADD + d;
  Qr[o]      = f2bf(q1 * c - q2 * sn);
  Qr[o + 64] = f2bf(q2 * c + q1 * sn);
}

// ---------------- RoPE K: QKVtmp cols [2048,2560) -> (B,NKV,S,HD) bf16 ---------
__global__ __launch_bounds__(256) void rope_k_kernel(
    const ushortT* __restrict__ QKVtmp, const float* __restrict__ cosT,
    const float* __restrict__ sinT, ushortT* __restrict__ Kr) {
  int idx = blockIdx.x * 256 + threadIdx.x;   // B*S*NKV*64 total
  int d = idx & 63;
  int t = idx >> 6;          // (b*S+s)*NKV + kvh
  int kvh = t & (NKVH - 1);
  int bs = t >> 2;
  int s = bs & (SEQ - 1);
  int b = bs >> 11;
  float c = cosT[s * HEADD + d], sn = sinT[s * HEADD + d];
  float k1 = bf2f(QKVtmp[(size_t)bs * QKVCOLS + 2048 + kvh * HEADD + d]);
  float k2 = bf2f(QKVtmp[(size_t)bs * QKVCOLS + 2048 + kvh * HEADD + d + 64]);
  size_t o = ((size_t)(b * NKVH + kvh) * SEQ + s) * HEADD + d;
  Kr[o]      = f2bf(k1 * c - k2 * sn);
  Kr[o + 64] = f2bf(k2 * c + k1 * sn);
}

// ---------------- V relayout: QKVtmp cols [2560,3072) -> (B,NKV,HD,S) ----------
__global__ __launch_bounds__(256) void v_relayout_kernel(
    const ushortT* __restrict__ QKVtmp, ushortT* __restrict__ Vt) {
  __shared__ ushortT tile[32][33];
  int bk = blockIdx.z;             // b*NKV + kvh
  int b = bk >> 2, kvh = bk & 3;
  int s0 = blockIdx.x * 32, d0 = blockIdx.y * 32;
  int tx = threadIdx.x & 31, ty = threadIdx.x >> 5;
#pragma unroll
  for (int i = 0; i < 4; ++i) {
    int s = s0 + ty + i * 8;
    tile[ty + i * 8][tx] =
        QKVtmp[(size_t)(b * SEQ + s) * QKVCOLS + 2560 + kvh * HEADD + d0 + tx];
  }
  __syncthreads();
#pragma unroll
  for (int i = 0; i < 4; ++i) {
    int d = d0 + ty + i * 8;
    Vt[((size_t)bk * HEADD + d) * SEQ + s0 + tx] = tile[tx][ty + i * 8];
  }
}

// ---------------- Flash attention (causal, GQA), BM=128 / BN=64 ----------------
// grid (32=bh fast, 16=paired q-block). 4 waves; each wave owns 32 q-rows
// (2 sub-tiles of 16). Scores computed TRANSPOSED (S^T = K·Q^T) so softmax
// over keys is in-lane (16 vals) + 2 shuffles, state is per-lane scalar, and
// P^T->B-operand needs only packed b64 LDS writes. O^T = V^T·P^T.
__global__ __launch_bounds__(256) void attn_kernel(
    const ushortT* __restrict__ Q,   // (B,NH,S,HD)
    const ushortT* __restrict__ Kg,  // (B,NKV,S,HD)
    const ushortT* __restrict__ Vg,  // (B,NKV,HD,S)
    ushortT* __restrict__ Oa) {      // (B,S,NH*HD)
  __shared__ __align__(16) ushortT lK[64 * 128];    // key x d, swizzled chunks
  __shared__ __align__(16) ushortT lV[128 * 64];    // d x key, swizzled chunks
  __shared__ __align__(16) ushortT lP[4 * 32 * 72]; // per-wave P (q x k), pad 72

  const int tid = threadIdx.x;
  const int w = tid >> 6, lane = tid & 63;
  const int g = lane >> 4, l15 = lane & 15;
  const int sw = l15 & 7;
  const int bh = blockIdx.x;
  const int b = bh >> 4, h = bh & 15;
  const int kvh = h >> 2;
  const int yi = blockIdx.y;
  const int qi = (yi < 8) ? (15 - yi) : (yi - 8);  // paired: CU gets 34 iters
  const int q0 = qi << 7;
  const int qw = q0 + w * 32;

  const float SC = 0.08838834764831845f * 1.4426950408889634f; // 1/sqrt(128)*log2e

  short8 qf[2][4];   // B-operand fragments of Q (q = qw + mt*16 + l15)
#pragma unroll
  for (int mt = 0; mt < 2; ++mt) {
    const ushortT* qp =
        Q + (((size_t)(b * NHD + h)) * SEQ + qw + mt * 16 + l15) * HEADD + g * 8;
#pragma unroll
    for (int ks = 0; ks < 4; ++ks) qf[mt][ks] = *(const short8*)(qp + ks * 32);
  }

  floatx4 o[2][8] = {};                       // O^T: col=q(l15), row=d(g*4+r)
  float m_s[2] = {-INFINITY, -INFINITY};
  float l_s[2] = {0.f, 0.f};

  const ushortT* kbase = Kg + ((size_t)(b * NKVH + kvh)) * SEQ * HEADD;
  const ushortT* vbase = Vg + ((size_t)(b * NKVH + kvh)) * HEADD * SEQ;
  ushortT* pw = lP + w * 32 * 72;

  const int nkt = 2 * qi + 2;
  for (int kt = 0; kt < nkt; ++kt) {
    __syncthreads();
#pragma unroll
    for (int ii = 0; ii < 4; ++ii) {          // K tile: 64 keys x 128 d
      int s = ii * 256 + tid;
      int r = s >> 4, j = (s & 15) ^ (r & 7);
      gload16(kbase + (size_t)(kt * 64 + r) * HEADD + j * 8, lK + s * 8);
    }
#pragma unroll
    for (int ii = 0; ii < 4; ++ii) {          // V^T tile: 128 d x 64 keys
      int s = ii * 256 + tid;
      int r = s >> 3, j = (s & 7) ^ (r & 7);
      gload16(vbase + (size_t)r * SEQ + kt * 64 + j * 8, lV + s * 8);
    }
    __syncthreads();

    // last k-tile is entirely above the diagonal for the lower-half waves
    if (kt == nkt - 1 && w < 2) continue;

    // S^T = K · Q^T : D col = q (l15), row = key (g*4+r), per nt key-16-block
    floatx4 sc[2][4] = {};
#pragma unroll
    for (int ks = 0; ks < 4; ++ks)
#pragma unroll
      for (int nt = 0; nt < 4; ++nt) {
        short8 kf = *(const short8*)(lK + (nt * 16 + l15) * 128 + ((ks * 4 + g) ^ sw) * 8);
        sc[0][nt] = __builtin_amdgcn_mfma_f32_16x16x32_bf16(kf, qf[0][ks], sc[0][nt], 0, 0, 0);
        sc[1][nt] = __builtin_amdgcn_mfma_f32_16x16x32_bf16(kf, qf[1][ks], sc[1][nt], 0, 0, 0);
      }

#pragma unroll
    for (int mt = 0; mt < 2; ++mt) {
      const int qsub = qw + mt * 16;               // + l15 per lane
      const bool needmask = (kt * 64 + 63) > qsub; // wave-uniform
      float ps[4][4];
      float mx = -INFINITY;
#pragma unroll
      for (int nt = 0; nt < 4; ++nt)
#pragma unroll
        for (int r = 0; r < 4; ++r) {
          float v = sc[mt][nt][r] * SC;
          if (needmask) {
            int kg = kt * 64 + nt * 16 + g * 4 + r;
            if (kg > qsub + l15) v = -INFINITY;
          }
          ps[nt][r] = v;
          mx = fmaxf(mx, v);
        }
      mx = fmaxf(mx, __shfl_xor(mx, 16));
      mx = fmaxf(mx, __shfl_xor(mx, 32));
      float mn = fmaxf(m_s[mt], mx);
      float alpha = __builtin_amdgcn_exp2f(m_s[mt] - mn);
      m_s[mt] = mn;
      float rs = 0.f;
#pragma unroll
      for (int nt = 0; nt < 4; ++nt) {
        ushort4v pk;
#pragma unroll
        for (int r = 0; r < 4; ++r) {
          float e = __builtin_amdgcn_exp2f(ps[nt][r] - mn);
          rs += e;
          ((ushortT*)&pk)[r] = f2bf(e);
        }
        // P[q_local][k]: row = mt*16+l15, k = nt*16 + g*4 .. +3 (b64 write)
        *(ushort4v*)(pw + (mt * 16 + l15) * 72 + nt * 16 + g * 4) = pk;
      }
      rs += __shfl_xor(rs, 16);
      rs += __shfl_xor(rs, 32);
      l_s[mt] = l_s[mt] * alpha + rs;
#pragma unroll
      for (int dt = 0; dt < 8; ++dt)
#pragma unroll
        for (int r = 0; r < 4; ++r) o[mt][dt][r] *= alpha;
    }

    // O^T += V^T · P^T   (A = V^T frag from lV, B = P^T frag from lP)
#pragma unroll
    for (int ks = 0; ks < 2; ++ks) {
      short8 bp0 = *(const short8*)(pw + (0 * 16 + l15) * 72 + ks * 32 + g * 8);
      short8 bp1 = *(const short8*)(pw + (1 * 16 + l15) * 72 + ks * 32 + g * 8);
#pragma unroll
      for (int dt = 0; dt < 8; ++dt) {
        short8 vf = *(const short8*)(lV + (dt * 16 + l15) * 64 + ((ks * 4 + g) ^ sw) * 8);
        o[0][dt] = __builtin_amdgcn_mfma_f32_16x16x32_bf16(vf, bp0, o[0][dt], 0, 0, 0);
        o[1][dt] = __builtin_amdgcn_mfma_f32_16x16x32_bf16(vf, bp1, o[1][dt], 0, 0, 0);
      }
    }
  }

  // epilogue: O^T -> Oa (B,S,NH*HD); q = qw+mt*16+l15, d = dt*16+g*4+r
#pragma unroll
  for (int mt = 0; mt < 2; ++mt) {
    float inv = 1.f / l_s[mt];
    int qg = qw + mt * 16 + l15;
#pragma unroll
    for (int dt = 0; dt < 8; ++dt) {
      ushort4v ov;
#pragma unroll
      for (int r = 0; r < 4; ++r) ((ushortT*)&ov)[r] = f2bf(o[mt][dt][r] * inv);
      *(ushort4v*)(Oa + (size_t)(b * SEQ + qg) * NQCOLS + h * HEADD + dt * 16 + g * 4) = ov;
    }
  }
}

extern "C" void kernel_launch(void* const* d_in, const int* in_sizes, int n_in,
                              void* d_out, int out_size, void* d_ws, size_t ws_size,
                              hipStream_t stream) {
  const float* x    = (const float*)d_in[0];
  const float* cosT = (const float*)d_in[1];
  const float* sinT = (const float*)d_in[2];
  const float* Wq   = (const float*)d_in[3];
  const float* Wkv  = (const float*)d_in[4];
  const float* Wo   = (const float*)d_in[5];

  char* ws = (char*)d_ws;
  // workspace layout (bytes)
  ushortT* x_bf   = (ushortT*)(ws + 0);          // 16777216
  ushortT* Wqkvt  = (ushortT*)(ws + 16777216);   // 12582912 (3072 x 2048 bf16)
  ushortT* Wot    = (ushortT*)(ws + 29360128);   //  8388608
  ushortT* QKVtmp = (ushortT*)(ws + 37748736);   // 25165824 (4096 x 3072 bf16)
  ushortT* Qr     = (ushortT*)(ws + 62914560);   // 16777216
  ushortT* Kr     = (ushortT*)(ws + 79691776);   //  4194304
  ushortT* Vt     = (ushortT*)(ws + 83886080);   //  4194304
  ushortT* Oattn  = QKVtmp;                      // alias; total 88080384

  // 1) casts / weight transposes (Wq|Wkv stacked into one N x K operand)
  cast_bf16_kernel<<<8192, 256, 0, stream>>>(x, x_bf, (MROWS * HDIM) / 4);
  transpose_cast_kernel<<<dim3(64, 64), 256, 0, stream>>>(Wq, Wqkvt, HDIM, NQCOLS);
  transpose_cast_kernel<<<dim3(32, 64), 256, 0, stream>>>(Wkv, Wqkvt + 2048 * 2048, HDIM, 1024);
  transpose_cast_kernel<<<dim3(64, 64), 256, 0, stream>>>(Wo, Wot, NQCOLS, HDIM);

  // 2) fused QKV projection: (4096 x 2048) x (2048 x 3072) -> 768 blocks, 3/CU
  gemm_bt_kernel<<<dim3(24, 32), 256, 0, stream>>>(x_bf, Wqkvt, QKVtmp, MROWS, QKVCOLS, HDIM, 0);

  // 3) rope + relayout
  rope_q_kernel<<<16384, 256, 0, stream>>>(QKVtmp, cosT, sinT, Qr);
  rope_k_kernel<<<4096, 256, 0, stream>>>(QKVtmp, cosT, sinT, Kr);
  v_relayout_kernel<<<dim3(64, 4, 8), 256, 0, stream>>>(QKVtmp, Vt);

  // 4) attention (BM=128 blocks: 512 total, paired long+short per CU)
  attn_kernel<<<dim3(32, 16), 256, 0, stream>>>(Qr, Kr, Vt, Oattn);

  // 5) output projection (fp32 out)
  gemm_bt_kernel<<<dim3(16, 32), 256, 0, stream>>>(Oattn, Wot, d_out, MROWS, HDIM, NQCOLS, 1);
}